// Round 4
// baseline (778.689 us; speedup 1.0000x reference)
//
#include <hip/hip_runtime.h>
#include <hip/hip_bf16.h>
#include <math.h>

#define HF 129
#define WF 129
#define BDIM 2
#define TOK (BDIM*HF*WF)   /* 33282 */
#define DMOD 128

typedef __attribute__((ext_vector_type(8))) short short8;
typedef __attribute__((ext_vector_type(8))) unsigned short ushort8;
typedef __attribute__((ext_vector_type(4))) float f32x4;

__device__ __forceinline__ float leaky(float v){ return v > 0.f ? v : 0.01f*v; }
__device__ __forceinline__ float bf2f(unsigned short u){ return __uint_as_float(((unsigned int)u) << 16); }
__device__ __forceinline__ unsigned short f2bf(float f){
    unsigned int u = __float_as_uint(f);
    unsigned int r = (u + 0x7fff + ((u >> 16) & 1)) >> 16;
    return (unsigned short)r;
}

// ---------------- one-shot weight prep: f32->bf16 (+ pad / transpose for conv weights) ----------------
#define NQ 147456
#define NPJ 49152
#define N1 196608
#define N2 196608
#define NPAT 8192
#define NDEP 8192
__global__ __launch_bounds__(256) void prep_weights(
    const float* __restrict__ qkv_w, const float* __restrict__ proj_w,
    const float* __restrict__ fc1_w, const float* __restrict__ fc2_w,
    const float* __restrict__ patch_w, const float* __restrict__ dep_w,
    __hip_bfloat16* __restrict__ wq, __hip_bfloat16* __restrict__ wp,
    __hip_bfloat16* __restrict__ w1, __hip_bfloat16* __restrict__ w2,
    __hip_bfloat16* __restrict__ wpat, __hip_bfloat16* __restrict__ wdep,
    float* __restrict__ zero64)
{
    int off = blockIdx.x*256 + threadIdx.x;
    if (off < NQ) { wq[off] = __float2bfloat16(qkv_w[off]); return; } off -= NQ;
    if (off < NPJ){ wp[off] = __float2bfloat16(proj_w[off]); return; } off -= NPJ;
    if (off < N1) { w1[off] = __float2bfloat16(fc1_w[off]); return; } off -= N1;
    if (off < N2) { w2[off] = __float2bfloat16(fc2_w[off]); return; } off -= N2;
    if (off < NPAT){ int r = off>>6, e = off&63;
        wpat[off] = __float2bfloat16(e < 48 ? patch_w[r*48 + e] : 0.f); return; } off -= NPAT;
    if (off < NDEP){ int e = off>>7, d = off&127;
        wdep[off] = __float2bfloat16(e < 48 ? dep_w[d*48 + e] : 0.f); return; } off -= NDEP;
    if (off < 64) zero64[off] = 0.f;
}

// ---------------- im2col for patchify: x*pos_w+pos_b, wrap, 4x4/stride2 -> [T,64] bf16 (48 used) ----------------
__global__ __launch_bounds__(256) void im2col_kernel(
    const float* __restrict__ x, const float* __restrict__ pos_w, const float* __restrict__ pos_b,
    __hip_bfloat16* __restrict__ G)
{
    __shared__ float xs[12][260];
    int blk = blockIdx.x;           // b*HF + oh
    int b = blk / HF, oh = blk - b*HF;
    int tid = threadIdx.x;
    #pragma unroll
    for (int it = 0; it < 3; ++it) {
        int p = it*4 + (tid >> 6);
        int c = p >> 2, r = p & 3;
        int h = (oh*2 + r - 2 + 256) & 255;
        int w4 = (tid & 63) * 4;
        float4 xv  = *(const float4*)(x     + ((size_t)(b*3 + c)*256 + h)*256 + w4);
        float4 pwv = *(const float4*)(pos_w + ((size_t)c*256 + h)*256 + w4);
        float4 pbv = *(const float4*)(pos_b + ((size_t)c*256 + h)*256 + w4);
        float4 o; o.x = xv.x*pwv.x + pbv.x; o.y = xv.y*pwv.y + pbv.y;
        o.z = xv.z*pwv.z + pbv.z; o.w = xv.w*pwv.w + pbv.w;
        *(float4*)&xs[p][w4] = o;
    }
    __syncthreads();
    int e = tid & 63, og = tid >> 6;
    int c = e >> 4, k = e & 15, kh = k >> 2, kw = k & 3;
    int p = c*4 + kh;
    unsigned short* Grow = (unsigned short*)G + (size_t)blk*WF*64;
    for (int ow = og; ow < WF; ow += 4) {
        unsigned short v = 0;
        if (e < 48) {
            int col = (ow*2 + kw - 2 + 256) & 255;
            v = f2bf(xs[p][col]);
        }
        Grow[ow*64 + e] = v;
    }
}

// ---------------- big-tile MFMA GEMM, optional fused LayerNorm on A ----------------
// BM=BN=128, K staged in full panels of 128. 256 threads = 4 waves (2x2), each wave 64x64.
// LNF=1: A is f32 [M,128]; LN (mean/var over 128) fused into staging (stats via shfl_xor pair).
// RES=1: Cf += result (f32); else Cbf = bf16 result. ACT=1: leaky relu.
template<int LNF, int ACT, int RES>
__global__ __launch_bounds__(256) void gemm2_kernel(
    const void* __restrict__ Av, const __hip_bfloat16* __restrict__ W,
    const float* __restrict__ bias, const float* __restrict__ lng, const float* __restrict__ lnb,
    __hip_bfloat16* __restrict__ Cbf, float* __restrict__ Cf, int M, int N, int K)
{
    __shared__ __align__(16) char As[128*256];
    __shared__ __align__(16) char Ws[128*256];
    int tid = threadIdx.x;
    int bm = blockIdx.x*128, bn = blockIdx.y*128;
    int lane = tid & 63, wid = tid >> 6;
    int wr = (wid >> 1)*64, wc = (wid & 1)*64;
    int lrow = lane & 15, lq = lane >> 4;
    int sr = tid >> 1, sh = tid & 1;        // staging: 2 threads per row
    int swz_w = (sr & 7) << 4;
    int swz_r = (lrow & 7) << 4;

    f32x4 acc[4][4] = {};
    for (int k0 = 0; k0 < K; k0 += 128) {
        if (k0) __syncthreads();
        // ---- stage W (always bf16, rows = output cols) ----
        {
            const char* wp = (const char*)(W + (size_t)(bn + sr)*K + k0) + sh*128;
            #pragma unroll
            for (int i = 0; i < 8; ++i) {
                int4 v = *(const int4*)(wp + i*16);
                *(int4*)(Ws + sr*256 + ((sh*128 + i*16) ^ swz_w)) = v;
            }
        }
        // ---- stage A ----
        bool vr = (bm + sr) < M;
        if (LNF == 0) {
            const char* ap = (const char*)((const __hip_bfloat16*)Av + (size_t)(bm + sr)*K + k0) + sh*128;
            int4 z = {0,0,0,0};
            #pragma unroll
            for (int i = 0; i < 8; ++i) {
                int4 v = vr ? *(const int4*)(ap + i*16) : z;
                *(int4*)(As + sr*256 + ((sh*128 + i*16) ^ swz_w)) = v;
            }
        } else {
            // A f32 [M,128]; this thread owns 64 contiguous floats of row sr
            const float* ap = (const float*)Av + (size_t)(bm + sr)*128 + sh*64;
            float4 vals[16];
            float s = 0.f, ss = 0.f;
            #pragma unroll
            for (int i = 0; i < 16; ++i) {
                float4 v = {0,0,0,0};
                if (vr) v = *(const float4*)(ap + i*4);
                vals[i] = v;
                s  += v.x + v.y + v.z + v.w;
                ss += v.x*v.x + v.y*v.y + v.z*v.z + v.w*v.w;
            }
            s += __shfl_xor(s, 1); ss += __shfl_xor(ss, 1);
            float mean = s * (1.f/128.f);
            float inv = rsqrtf(ss * (1.f/128.f) - mean*mean + 1e-5f);
            #pragma unroll
            for (int j = 0; j < 8; ++j) {
                int c0 = sh*64 + j*8;
                float4 g0 = *(const float4*)(lng + c0);
                float4 g1 = *(const float4*)(lng + c0 + 4);
                float4 b0 = *(const float4*)(lnb + c0);
                float4 b1 = *(const float4*)(lnb + c0 + 4);
                float4 u = vals[j*2], u2 = vals[j*2+1];
                int4 pk;
                pk.x = f2bf((u.x -mean)*inv*g0.x + b0.x) | (f2bf((u.y -mean)*inv*g0.y + b0.y) << 16);
                pk.y = f2bf((u.z -mean)*inv*g0.z + b0.z) | (f2bf((u.w -mean)*inv*g0.w + b0.w) << 16);
                pk.z = f2bf((u2.x-mean)*inv*g1.x + b1.x) | (f2bf((u2.y-mean)*inv*g1.y + b1.y) << 16);
                pk.w = f2bf((u2.z-mean)*inv*g1.z + b1.z) | (f2bf((u2.w-mean)*inv*g1.w + b1.w) << 16);
                *(int4*)(As + sr*256 + ((sh*128 + j*16) ^ swz_w)) = pk;
            }
        }
        __syncthreads();
        // ---- compute: 4 k-slices x (4x4) 16x16 frags per wave ----
        #pragma unroll
        for (int ks = 0; ks < 4; ++ks) {
            short8 af[4], bfr[4];
            #pragma unroll
            for (int mi = 0; mi < 4; ++mi)
                af[mi] = *(const short8*)(As + (wr + mi*16 + lrow)*256 + ((ks*64 + lq*16) ^ swz_r));
            #pragma unroll
            for (int ni = 0; ni < 4; ++ni)
                bfr[ni] = *(const short8*)(Ws + (wc + ni*16 + lrow)*256 + ((ks*64 + lq*16) ^ swz_r));
            #pragma unroll
            for (int mi = 0; mi < 4; ++mi)
                #pragma unroll
                for (int ni = 0; ni < 4; ++ni)
                    acc[mi][ni] = __builtin_amdgcn_mfma_f32_16x16x32_bf16(af[mi], bfr[ni], acc[mi][ni], 0, 0, 0);
        }
    }
    // ---- epilogue: C/D layout col=lane&15, row=(lane>>4)*4+reg ----
    #pragma unroll
    for (int ni = 0; ni < 4; ++ni) {
        int col = bn + wc + ni*16 + lrow;
        float bv = bias[col];
        #pragma unroll
        for (int mi = 0; mi < 4; ++mi) {
            #pragma unroll
            for (int r = 0; r < 4; ++r) {
                int row = bm + wr + mi*16 + lq*4 + r;
                if (row >= M) continue;
                float v = acc[mi][ni][r] + bv;
                if (ACT) v = leaky(v);
                if (RES) Cf[(size_t)row*N + col] += v;
                else     Cbf[(size_t)row*N + col] = __float2bfloat16(v);
            }
        }
    }
}

// ---------------- small 64x64 MFMA GEMM (conv GEMMs: K=64 / N=64 cases) ----------------
template<int ACT, int RES, int OUTF, int A32>
__global__ __launch_bounds__(256) void mgemm_kernel(
    const void* __restrict__ Av, const __hip_bfloat16* __restrict__ W,
    const float* __restrict__ bias, __hip_bfloat16* __restrict__ Cbf,
    float* __restrict__ Cres, int M, int N, int K)
{
    __shared__ __align__(16) char As[64*128];
    __shared__ __align__(16) char Ws[64*128];
    int tid = threadIdx.x;
    int bm = blockIdx.x*64, bn = blockIdx.y*64;
    int lane = tid & 63, wid = tid >> 6;
    int wm = (wid >> 1)*32, wn = (wid & 1)*32;
    int lrow = lane & 15, lq = lane >> 4;
    int srow = tid >> 3, scg = tid & 7;
    int wo0 = ((srow     )*128 + scg*16) ^ ((srow&7)<<4);
    int wo1 = ((srow + 32)*128 + scg*16) ^ ((srow&7)<<4);
    int swz = (lrow & 7) << 4;
    int baseA0 = (wm + lrow     )*128 + lq*16;
    int baseA1 = (wm + 16 + lrow)*128 + lq*16;
    int baseB0 = (wn + lrow     )*128 + lq*16;
    int baseB1 = (wn + 16 + lrow)*128 + lq*16;

    f32x4 acc[2][2] = {};
    bool v0 = (bm + srow) < M, v1 = (bm + srow + 32) < M;
    const __hip_bfloat16* a0p = (const __hip_bfloat16*)Av + (size_t)(bm + srow)*K + scg*8;
    const __hip_bfloat16* a1p = (const __hip_bfloat16*)Av + (size_t)(bm + srow + 32)*K + scg*8;
    const float* a0pf = (const float*)Av + (size_t)(bm + srow)*K + scg*8;
    const float* a1pf = (const float*)Av + (size_t)(bm + srow + 32)*K + scg*8;
    const __hip_bfloat16* w0p = W + (size_t)(bn + srow)*K + scg*8;
    const __hip_bfloat16* w1p = W + (size_t)(bn + srow + 32)*K + scg*8;

    for (int k0 = 0; k0 < K; k0 += 64) {
        int4 va0 = {}, va1 = {};
        if (A32) {
            if (v0) {
                float4 p0 = *(const float4*)(a0pf + k0);
                float4 p1 = *(const float4*)(a0pf + k0 + 4);
                va0.x = f2bf(p0.x) | (f2bf(p0.y) << 16); va0.y = f2bf(p0.z) | (f2bf(p0.w) << 16);
                va0.z = f2bf(p1.x) | (f2bf(p1.y) << 16); va0.w = f2bf(p1.z) | (f2bf(p1.w) << 16);
            }
            if (v1) {
                float4 p0 = *(const float4*)(a1pf + k0);
                float4 p1 = *(const float4*)(a1pf + k0 + 4);
                va1.x = f2bf(p0.x) | (f2bf(p0.y) << 16); va1.y = f2bf(p0.z) | (f2bf(p0.w) << 16);
                va1.z = f2bf(p1.x) | (f2bf(p1.y) << 16); va1.w = f2bf(p1.z) | (f2bf(p1.w) << 16);
            }
        } else {
            if (v0) va0 = *(const int4*)(a0p + k0);
            if (v1) va1 = *(const int4*)(a1p + k0);
        }
        int4 vw0 = *(const int4*)(w0p + k0);
        int4 vw1 = *(const int4*)(w1p + k0);
        __syncthreads();
        *(int4*)(As + wo0) = va0;
        *(int4*)(As + wo1) = va1;
        *(int4*)(Ws + wo0) = vw0;
        *(int4*)(Ws + wo1) = vw1;
        __syncthreads();
        #pragma unroll
        for (int ks = 0; ks < 2; ++ks) {
            int kb = ks*64;
            short8 a0 = *(const short8*)(As + ((baseA0 + kb) ^ swz));
            short8 a1 = *(const short8*)(As + ((baseA1 + kb) ^ swz));
            short8 b0 = *(const short8*)(Ws + ((baseB0 + kb) ^ swz));
            short8 b1 = *(const short8*)(Ws + ((baseB1 + kb) ^ swz));
            acc[0][0] = __builtin_amdgcn_mfma_f32_16x16x32_bf16(a0, b0, acc[0][0], 0, 0, 0);
            acc[0][1] = __builtin_amdgcn_mfma_f32_16x16x32_bf16(a0, b1, acc[0][1], 0, 0, 0);
            acc[1][0] = __builtin_amdgcn_mfma_f32_16x16x32_bf16(a1, b0, acc[1][0], 0, 0, 0);
            acc[1][1] = __builtin_amdgcn_mfma_f32_16x16x32_bf16(a1, b1, acc[1][1], 0, 0, 0);
        }
    }
    float bv0 = bias[bn + wn + lrow];
    float bv1 = bias[bn + wn + 16 + lrow];
    #pragma unroll
    for (int mi = 0; mi < 2; ++mi) {
        #pragma unroll
        for (int r = 0; r < 4; ++r) {
            int row = bm + wm + mi*16 + lq*4 + r;
            if (row >= M) continue;
            #pragma unroll
            for (int ni = 0; ni < 2; ++ni) {
                float v = acc[mi][ni][r] + (ni ? bv1 : bv0);
                if (ACT == 1) v = leaky(v);
                int col = bn + wn + ni*16 + lrow;
                if (RES)       Cres[(size_t)row*N + col] += v;
                else if (OUTF) Cres[(size_t)row*N + col] = v;
                else           Cbf[(size_t)row*N + col] = __float2bfloat16(v);
            }
        }
    }
}

// ---------------- neighborhood attention (bf16 in/out): one thread per (token, head) ----------------
__global__ __launch_bounds__(256) void attn_kernel(const __hip_bfloat16* __restrict__ qkv,
    const float* __restrict__ rpb, __hip_bfloat16* __restrict__ o)
{
    int gid = blockIdx.x*256 + threadIdx.x;
    int tok = gid >> 3;
    if (tok >= TOK) return;
    int head = gid & 7;
    int b = tok / (HF*WF);
    int rem = tok - b*HF*WF;
    int y = rem / WF, x = rem - y*WF;
    const ushort8* qp = (const ushort8*)(qkv + (size_t)tok*384 + head*16);
    float q[16];
    {
        ushort8 u0 = qp[0], u1 = qp[1];
        #pragma unroll
        for (int i = 0; i < 8; ++i) { q[i] = bf2f(u0[i])*0.25f; q[i+8] = bf2f(u1[i])*0.25f; }
    }
    float logits[25];
    float mx = -1e30f;
    #pragma unroll
    for (int di = -2; di <= 2; ++di) {
        int ny = y + di; ny += (ny < 0) ? HF : 0; ny -= (ny >= HF) ? HF : 0;
        #pragma unroll
        for (int dj = -2; dj <= 2; ++dj) {
            int nx = x + dj; nx += (nx < 0) ? WF : 0; nx -= (nx >= WF) ? WF : 0;
            size_t nt = (size_t)((b*HF + ny)*WF + nx);
            const ushort8* kp = (const ushort8*)(qkv + nt*384 + 128 + head*16);
            ushort8 k0 = kp[0], k1 = kp[1];
            float d = 0.f;
            #pragma unroll
            for (int i = 0; i < 8; ++i) d += q[i]*bf2f(k0[i]) + q[i+8]*bf2f(k1[i]);
            d += rpb[head*81 + (di+4)*9 + (dj+4)];
            logits[(di+2)*5 + (dj+2)] = d;
            mx = fmaxf(mx, d);
        }
    }
    float s = 0.f;
    #pragma unroll
    for (int n = 0; n < 25; ++n) { float p = __expf(logits[n]-mx); logits[n] = p; s += p; }
    float invs = 1.f/s;
    float outv[16] = {};
    #pragma unroll
    for (int di = -2; di <= 2; ++di) {
        int ny = y + di; ny += (ny < 0) ? HF : 0; ny -= (ny >= HF) ? HF : 0;
        #pragma unroll
        for (int dj = -2; dj <= 2; ++dj) {
            int nx = x + dj; nx += (nx < 0) ? WF : 0; nx -= (nx >= WF) ? WF : 0;
            size_t nt = (size_t)((b*HF + ny)*WF + nx);
            const ushort8* vp = (const ushort8*)(qkv + nt*384 + 256 + head*16);
            ushort8 v0 = vp[0], v1 = vp[1];
            float p = logits[(di+2)*5 + (dj+2)];
            #pragma unroll
            for (int i = 0; i < 8; ++i) { outv[i] += p*bf2f(v0[i]); outv[i+8] += p*bf2f(v1[i]); }
        }
    }
    __hip_bfloat16* op = o + (size_t)tok*DMOD + head*16;
    #pragma unroll
    for (int i = 0; i < 16; ++i) op[i] = __float2bfloat16(outv[i]*invs);
}

// ---------------- depatch gather: y[b,c,i,j] = db[c] + 4 taps of G ----------------
__global__ __launch_bounds__(256) void degather_kernel(const float* __restrict__ G,
    const float* __restrict__ db, float* __restrict__ yimg)
{
    int idx = blockIdx.x*256 + threadIdx.x;
    int b = idx >> 16;
    int pix = idx & 65535;
    int i = pix >> 8, j = pix & 255;
    int fh0 = i >> 1, fw0 = j >> 1;
    size_t r00 = ((size_t)(b*HF + fh0)*WF + fw0)*64;
    size_t r01 = r00 + 64;
    size_t r10 = r00 + (size_t)WF*64;
    size_t r11 = r10 + 64;
    int wr0 = (2 + (i & 1))*4, wr1 = (i & 1)*4;
    int wc0 = 2 + (j & 1), wc1 = (j & 1);
    #pragma unroll
    for (int c = 0; c < 3; ++c) {
        int e = c*16;
        float v = db[c]
                + G[r00 + e + wr0 + wc0] + G[r01 + e + wr0 + wc1]
                + G[r10 + e + wr1 + wc0] + G[r11 + e + wr1 + wc1];
        yimg[((size_t)(b*3 + c) << 16) + pix] = v;
    }
}

// ---------------- residual conv tail: out = y + conv1x1(leaky(conv5x5_wrap(y))) ----------------
__global__ __launch_bounds__(256) void res_kernel(const float* __restrict__ y,
    const float* __restrict__ w1, const float* __restrict__ b1,
    const float* __restrict__ w2, const float* __restrict__ b2, float* __restrict__ out)
{
    int idx = blockIdx.x*256 + threadIdx.x;
    int b = idx >> 16;
    int pix = idx & 65535;
    int i = pix >> 8, j = pix & 255;
    float yv[3][5][5];
    #pragma unroll
    for (int c = 0; c < 3; ++c) {
        #pragma unroll
        for (int u = 0; u < 5; ++u) {
            int ii = (i + u - 2 + 256) & 255;
            #pragma unroll
            for (int v = 0; v < 5; ++v) {
                int jj = (j + v - 2 + 256) & 255;
                yv[c][u][v] = y[((size_t)(b*3 + c)*256 + ii)*256 + jj];
            }
        }
    }
    float r1[12];
    #pragma unroll
    for (int rc = 0; rc < 12; ++rc) {
        float a = b1[rc];
        #pragma unroll
        for (int c = 0; c < 3; ++c)
            #pragma unroll
            for (int u = 0; u < 5; ++u)
                #pragma unroll
                for (int v = 0; v < 5; ++v)
                    a += yv[c][u][v] * w1[rc*75 + c*25 + u*5 + v];
        r1[rc] = leaky(a);
    }
    #pragma unroll
    for (int c = 0; c < 3; ++c) {
        float a = b2[c];
        #pragma unroll
        for (int rc = 0; rc < 12; ++rc) a += r1[rc]*w2[c*12 + rc];
        out[((size_t)(b*3 + c)*256 + i)*256 + j] = yv[c][2][2] + a;
    }
}

extern "C" void kernel_launch(void* const* d_in, const int* in_sizes, int n_in,
                              void* d_out, int out_size, void* d_ws, size_t ws_size,
                              hipStream_t stream)
{
    const float* x      = (const float*)d_in[0];
    const float* pos_w  = (const float*)d_in[1];
    const float* pos_b  = (const float*)d_in[2];
    const float* patch_w= (const float*)d_in[3];
    const float* patch_b= (const float*)d_in[4];
    const float* ln1_g  = (const float*)d_in[5];
    const float* ln1_b  = (const float*)d_in[6];
    const float* qkv_w  = (const float*)d_in[7];
    const float* qkv_b  = (const float*)d_in[8];
    const float* rpb    = (const float*)d_in[9];
    const float* proj_w = (const float*)d_in[10];
    const float* proj_b = (const float*)d_in[11];
    const float* ln2_g  = (const float*)d_in[12];
    const float* ln2_b  = (const float*)d_in[13];
    const float* fc1_w  = (const float*)d_in[14];
    const float* fc1_b  = (const float*)d_in[15];
    const float* fc2_w  = (const float*)d_in[16];
    const float* fc2_b  = (const float*)d_in[17];
    const float* dep_w  = (const float*)d_in[18];
    const float* dep_b  = (const float*)d_in[19];
    const float* rc1_w  = (const float*)d_in[20];
    const float* rc1_b  = (const float*)d_in[21];
    const float* rc2_w  = (const float*)d_in[22];
    const float* rc2_b  = (const float*)d_in[23];

    const size_t SZ = (size_t)TOK * 128;
    char* w = (char*)d_ws;
    float* f            = (float*)w;            w += SZ*4;
    __hip_bfloat16* yln = (__hip_bfloat16*)w;   w += SZ*2;          // attn output
    __hip_bfloat16* qkvb= (__hip_bfloat16*)w;   w += (size_t)TOK*384*2;
    __hip_bfloat16* hb  = (__hip_bfloat16*)w;   w += (size_t)TOK*512*2;
    float* yimg         = (float*)w;            w += (size_t)BDIM*3*65536*4;
    __hip_bfloat16* wq  = (__hip_bfloat16*)w;   w += (size_t)NQ*2;
    __hip_bfloat16* wp  = (__hip_bfloat16*)w;   w += (size_t)NPJ*2;
    __hip_bfloat16* w1  = (__hip_bfloat16*)w;   w += (size_t)N1*2;
    __hip_bfloat16* w2  = (__hip_bfloat16*)w;   w += (size_t)N2*2;
    __hip_bfloat16* wpat= (__hip_bfloat16*)w;   w += (size_t)NPAT*2;
    __hip_bfloat16* wdep= (__hip_bfloat16*)w;   w += (size_t)NDEP*2;
    float* zero64       = (float*)w;            w += 64*4;

    // disjoint lifetimes: im2col output aliases qkvb, depatch G aliases hb
    __hip_bfloat16* icol = qkvb;    // TOK*64 bf16
    float* G             = (float*)hb;  // TOK*64 f32

    const int PREP_TOT = NQ + NPJ + N1 + N2 + NPAT + NDEP + 64;
    prep_weights<<<(PREP_TOT + 255)/256, 256, 0, stream>>>(
        qkv_w, proj_w, fc1_w, fc2_w, patch_w, dep_w, wq, wp, w1, w2, wpat, wdep, zero64);

    im2col_kernel<<<BDIM*HF, 256, 0, stream>>>(x, pos_w, pos_b, icol);

    const int GM64 = (TOK + 63)/64;     // 521
    const int GM  = (TOK + 127)/128;    // 261

    // patchify GEMM: [T,64] @ wpat[128,64]^T -> f (f32)
    mgemm_kernel<0,0,1,0><<<dim3(GM64,2), 256, 0, stream>>>(icol, wpat, patch_b,
        nullptr, f, TOK, 128, 64);

    for (int l = 0; l < 3; ++l) {
        // qkv = LN1(f) @ Wq^T + b  (LN fused)
        gemm2_kernel<1,0,0><<<dim3(GM,3), 256, 0, stream>>>(f, wq + (size_t)l*384*128,
            qkv_b + l*384, ln1_g + l*128, ln1_b + l*128, qkvb, nullptr, TOK, 384, 128);
        attn_kernel<<<(TOK*8 + 255)/256, 256, 0, stream>>>(qkvb, rpb + l*8*81, yln);
        // f += attn_out @ Wp^T + b
        gemm2_kernel<0,0,1><<<dim3(GM,1), 256, 0, stream>>>(yln, wp + (size_t)l*128*128,
            proj_b + l*128, nullptr, nullptr, nullptr, f, TOK, 128, 128);
        // hb = leaky(LN2(f) @ W1^T + b)  (LN fused)
        gemm2_kernel<1,1,0><<<dim3(GM,4), 256, 0, stream>>>(f, w1 + (size_t)l*512*128,
            fc1_b + l*512, ln2_g + l*128, ln2_b + l*128, hb, nullptr, TOK, 512, 128);
        // f += hb @ W2^T + b
        gemm2_kernel<0,0,1><<<dim3(GM,1), 256, 0, stream>>>(hb, w2 + (size_t)l*128*512,
            fc2_b + l*128, nullptr, nullptr, nullptr, f, TOK, 128, 512);
    }

    // depatchify: G[T,64] = f[T,128] @ wdep[64,128]^T
    mgemm_kernel<0,0,1,1><<<dim3(GM64,1), 256, 0, stream>>>(f, wdep, zero64,
        nullptr, G, TOK, 64, 128);
    degather_kernel<<<512, 256, 0, stream>>>(G, dep_b, yimg);

    res_kernel<<<512, 256, 0, stream>>>(yimg, rc1_w, rc1_b, rc2_w, rc2_b, (float*)d_out);
}

// Round 5
// 361.257 us; speedup vs baseline: 2.1555x; 2.1555x over previous
//
#include <hip/hip_runtime.h>
#include <hip/hip_bf16.h>
#include <math.h>

#define HF 129
#define WF 129
#define BDIM 2
#define TOK (BDIM*HF*WF)   /* 33282 */
#define DMOD 128

typedef __attribute__((ext_vector_type(8))) short short8;
typedef __attribute__((ext_vector_type(8))) unsigned short ushort8;
typedef __attribute__((ext_vector_type(4))) float f32x4;

__device__ __forceinline__ float leaky(float v){ return v > 0.f ? v : 0.01f*v; }
__device__ __forceinline__ float bf2f(unsigned short u){ return __uint_as_float(((unsigned int)u) << 16); }
__device__ __forceinline__ unsigned short f2bf(float f){
    unsigned int u = __float_as_uint(f);
    unsigned int r = (u + 0x7fff + ((u >> 16) & 1)) >> 16;
    return (unsigned short)r;
}

// ---------------- one-shot weight prep ----------------
#define NQ 147456
#define NPJ 49152
#define N1 196608
#define N2 196608
#define NPAT 8192
#define NDEP 8192
__global__ __launch_bounds__(256) void prep_weights(
    const float* __restrict__ qkv_w, const float* __restrict__ proj_w,
    const float* __restrict__ fc1_w, const float* __restrict__ fc2_w,
    const float* __restrict__ patch_w, const float* __restrict__ dep_w,
    __hip_bfloat16* __restrict__ wq, __hip_bfloat16* __restrict__ wp,
    __hip_bfloat16* __restrict__ w1, __hip_bfloat16* __restrict__ w2,
    __hip_bfloat16* __restrict__ wpat, __hip_bfloat16* __restrict__ wdep,
    float* __restrict__ zero64)
{
    int off = blockIdx.x*256 + threadIdx.x;
    if (off < NQ) { wq[off] = __float2bfloat16(qkv_w[off]); return; } off -= NQ;
    if (off < NPJ){ wp[off] = __float2bfloat16(proj_w[off]); return; } off -= NPJ;
    if (off < N1) { w1[off] = __float2bfloat16(fc1_w[off]); return; } off -= N1;
    if (off < N2) { w2[off] = __float2bfloat16(fc2_w[off]); return; } off -= N2;
    if (off < NPAT){ int r = off>>6, e = off&63;
        wpat[off] = __float2bfloat16(e < 48 ? patch_w[r*48 + e] : 0.f); return; } off -= NPAT;
    if (off < NDEP){ int e = off>>7, d = off&127;
        wdep[off] = __float2bfloat16(e < 48 ? dep_w[d*48 + e] : 0.f); return; } off -= NDEP;
    if (off < 64) zero64[off] = 0.f;
}

// ---------------- im2col for patchify: x*pos_w+pos_b, wrap, 4x4/stride2 -> [T,64] bf16 (48 used) ----------------
__global__ __launch_bounds__(256) void im2col_kernel(
    const float* __restrict__ x, const float* __restrict__ pos_w, const float* __restrict__ pos_b,
    __hip_bfloat16* __restrict__ G)
{
    __shared__ float xs[12][260];
    int blk = blockIdx.x;           // b*HF + oh
    int b = blk / HF, oh = blk - b*HF;
    int tid = threadIdx.x;
    #pragma unroll
    for (int it = 0; it < 3; ++it) {
        int p = it*4 + (tid >> 6);
        int c = p >> 2, r = p & 3;
        int h = (oh*2 + r - 2 + 256) & 255;
        int w4 = (tid & 63) * 4;
        float4 xv  = *(const float4*)(x     + ((size_t)(b*3 + c)*256 + h)*256 + w4);
        float4 pwv = *(const float4*)(pos_w + ((size_t)c*256 + h)*256 + w4);
        float4 pbv = *(const float4*)(pos_b + ((size_t)c*256 + h)*256 + w4);
        float4 o; o.x = xv.x*pwv.x + pbv.x; o.y = xv.y*pwv.y + pbv.y;
        o.z = xv.z*pwv.z + pbv.z; o.w = xv.w*pwv.w + pbv.w;
        *(float4*)&xs[p][w4] = o;
    }
    __syncthreads();
    int e = tid & 63, og = tid >> 6;
    int c = e >> 4, k = e & 15, kh = k >> 2, kw = k & 3;
    int p = c*4 + kh;
    unsigned short* Grow = (unsigned short*)G + (size_t)blk*WF*64;
    for (int ow = og; ow < WF; ow += 4) {
        unsigned short v = 0;
        if (e < 48) {
            int col = (ow*2 + kw - 2 + 256) & 255;
            v = f2bf(xs[p][col]);
        }
        Grow[ow*64 + e] = v;
    }
}

// ---------------- gemmF: BM=64, BN=128, BK=64-chunk MFMA GEMM with optional epilogue LN ----------------
// 256 threads = 4 waves (2 row-groups x 2 col-halves), each wave 32x64 out (2x4 16x16 frags).
// Round-3-proven LDS layout: 128 B rows, XOR swizzle byte ^= (row&7)<<4, conflict-free.
// RES: Cf[row,col] += v (N must be 128). OUTF: Cf = v. else Cbf = bf16(v).
// LNE: after f-write, row LayerNorm over the 128 cols (cross-wave via lnred) -> yl bf16.
template<int ACT, int RES, int OUTF, int LNE>
__global__ __launch_bounds__(256) void gemmF_kernel(
    const __hip_bfloat16* __restrict__ A, const __hip_bfloat16* __restrict__ W,
    const float* __restrict__ bias, const float* __restrict__ lng, const float* __restrict__ lnb,
    __hip_bfloat16* __restrict__ Cbf, float* __restrict__ Cf,
    __hip_bfloat16* __restrict__ yl, int M, int N, int K)
{
    __shared__ __align__(16) char As[64*128];    // 8 KB  (one 64-chunk)
    __shared__ __align__(16) char Ws[128*128];   // 16 KB
    __shared__ float2 lnred[64][2];
    int tid = threadIdx.x;
    int bm = blockIdx.x*64, bn = blockIdx.y*128;
    int lane = tid & 63, wid = tid >> 6;
    int wr = (wid >> 1)*32, wc = (wid & 1)*64;
    int lrow = lane & 15, lq = lane >> 4;
    int srow = tid >> 3, scg = tid & 7;
    int swz = (lrow & 7) << 4;
    // staging LDS offsets (A: rows srow, srow+32; W: srow, +32, +64, +96)
    int awo0 = ((srow     )*128 + scg*16) ^ ((srow&7)<<4);
    int awo1 = ((srow + 32)*128 + scg*16) ^ ((srow&7)<<4);

    bool v0 = (bm + srow) < M, v1 = (bm + srow + 32) < M;
    const __hip_bfloat16* a0p = A + (size_t)(bm + srow)*K + scg*8;
    const __hip_bfloat16* a1p = A + (size_t)(bm + srow + 32)*K + scg*8;
    const __hip_bfloat16* wp0 = W + (size_t)(bn + srow)*K + scg*8;

    f32x4 acc[2][4] = {};
    for (int k0 = 0; k0 < K; k0 += 64) {
        int4 va0 = {}, va1 = {};
        if (v0) va0 = *(const int4*)(a0p + k0);
        if (v1) va1 = *(const int4*)(a1p + k0);
        int4 vw0 = *(const int4*)(wp0 + k0);
        int4 vw1 = *(const int4*)(wp0 + (size_t)32*K + k0);
        int4 vw2 = *(const int4*)(wp0 + (size_t)64*K + k0);
        int4 vw3 = *(const int4*)(wp0 + (size_t)96*K + k0);
        __syncthreads();   // protect previous-iteration LDS reads
        *(int4*)(As + awo0) = va0;
        *(int4*)(As + awo1) = va1;
        *(int4*)(Ws + awo0) = vw0;
        *(int4*)(Ws + awo1) = vw1;
        *(int4*)(Ws + (((srow+64)*128 + scg*16) ^ ((srow&7)<<4))) = vw2;
        *(int4*)(Ws + (((srow+96)*128 + scg*16) ^ ((srow&7)<<4))) = vw3;
        __syncthreads();
        #pragma unroll
        for (int ks = 0; ks < 2; ++ks) {
            int kb = ks*64;
            short8 af[2], bf[4];
            #pragma unroll
            for (int mi = 0; mi < 2; ++mi)
                af[mi] = *(const short8*)(As + (((wr + mi*16 + lrow)*128 + kb + lq*16) ^ swz));
            #pragma unroll
            for (int ni = 0; ni < 4; ++ni)
                bf[ni] = *(const short8*)(Ws + (((wc + ni*16 + lrow)*128 + kb + lq*16) ^ swz));
            #pragma unroll
            for (int mi = 0; mi < 2; ++mi)
                #pragma unroll
                for (int ni = 0; ni < 4; ++ni)
                    acc[mi][ni] = __builtin_amdgcn_mfma_f32_16x16x32_bf16(af[mi], bf[ni], acc[mi][ni], 0, 0, 0);
        }
    }
    // ---- epilogue. C/D layout: col=lane&15, row=(lane>>4)*4+reg ----
    float bcol[4];
    #pragma unroll
    for (int ni = 0; ni < 4; ++ni) bcol[ni] = bias[bn + wc + ni*16 + lrow];
    #pragma unroll
    for (int mi = 0; mi < 2; ++mi) {
        #pragma unroll
        for (int r = 0; r < 4; ++r) {
            int row = bm + wr + mi*16 + lq*4 + r;
            bool vrow = row < M;
            #pragma unroll
            for (int ni = 0; ni < 4; ++ni) {
                float v = acc[mi][ni][r] + bcol[ni];
                if (ACT) v = leaky(v);
                if (RES || OUTF) {
                    int col = wc + ni*16 + lrow;
                    size_t idx = (size_t)row*128 + col;
                    if (RES) { float old = vrow ? Cf[idx] : 0.f; v += old; }
                    if (vrow) Cf[idx] = v;
                } else {
                    int col = bn + wc + ni*16 + lrow;
                    if (vrow) Cbf[(size_t)row*N + col] = __float2bfloat16(v);
                }
                acc[mi][ni][r] = v;   // keep for LN
            }
        }
    }
    if (LNE) {
        float sa[8], ssa[8];
        #pragma unroll
        for (int mi = 0; mi < 2; ++mi)
            #pragma unroll
            for (int r = 0; r < 4; ++r) {
                float s = 0.f, ss = 0.f;
                #pragma unroll
                for (int ni = 0; ni < 4; ++ni) { float v = acc[mi][ni][r]; s += v; ss += v*v; }
                sa[mi*4+r] = s; ssa[mi*4+r] = ss;
            }
        #pragma unroll
        for (int m = 1; m < 16; m <<= 1) {
            #pragma unroll
            for (int i = 0; i < 8; ++i) { sa[i] += __shfl_xor(sa[i], m); ssa[i] += __shfl_xor(ssa[i], m); }
        }
        if (lrow == 0) {
            #pragma unroll
            for (int i = 0; i < 8; ++i)
                lnred[wr + (i>>2)*16 + lq*4 + (i&3)][wc>>6] = make_float2(sa[i], ssa[i]);
        }
        __syncthreads();
        float gcol[4], bbcol[4];
        #pragma unroll
        for (int ni = 0; ni < 4; ++ni) {
            gcol[ni] = lng[wc + ni*16 + lrow];
            bbcol[ni] = lnb[wc + ni*16 + lrow];
        }
        #pragma unroll
        for (int mi = 0; mi < 2; ++mi) {
            #pragma unroll
            for (int r = 0; r < 4; ++r) {
                int rl = wr + mi*16 + lq*4 + r;
                int row = bm + rl;
                if (row >= M) continue;
                float2 h0 = lnred[rl][0], h1 = lnred[rl][1];
                float mean = (h0.x + h1.x) * (1.f/128.f);
                float var = (h0.y + h1.y) * (1.f/128.f) - mean*mean;
                float inv = rsqrtf(var + 1e-5f);
                #pragma unroll
                for (int ni = 0; ni < 4; ++ni) {
                    int col = wc + ni*16 + lrow;
                    float yv = (acc[mi][ni][r] - mean)*inv*gcol[ni] + bbcol[ni];
                    yl[(size_t)row*128 + col] = __float2bfloat16(yv);
                }
            }
        }
    }
}

// ---------------- small 64x64 MFMA GEMM (depatch only: A f32 [T,128] -> G [T,64]) ----------------
template<int ACT, int RES, int OUTF, int A32>
__global__ __launch_bounds__(256) void mgemm_kernel(
    const void* __restrict__ Av, const __hip_bfloat16* __restrict__ W,
    const float* __restrict__ bias, __hip_bfloat16* __restrict__ Cbf,
    float* __restrict__ Cres, int M, int N, int K)
{
    __shared__ __align__(16) char As[64*128];
    __shared__ __align__(16) char Ws[64*128];
    int tid = threadIdx.x;
    int bm = blockIdx.x*64, bn = blockIdx.y*64;
    int lane = tid & 63, wid = tid >> 6;
    int wm = (wid >> 1)*32, wn = (wid & 1)*32;
    int lrow = lane & 15, lq = lane >> 4;
    int srow = tid >> 3, scg = tid & 7;
    int wo0 = ((srow     )*128 + scg*16) ^ ((srow&7)<<4);
    int wo1 = ((srow + 32)*128 + scg*16) ^ ((srow&7)<<4);
    int swz = (lrow & 7) << 4;
    int baseA0 = (wm + lrow     )*128 + lq*16;
    int baseA1 = (wm + 16 + lrow)*128 + lq*16;
    int baseB0 = (wn + lrow     )*128 + lq*16;
    int baseB1 = (wn + 16 + lrow)*128 + lq*16;

    f32x4 acc[2][2] = {};
    bool v0 = (bm + srow) < M, v1 = (bm + srow + 32) < M;
    const __hip_bfloat16* a0p = (const __hip_bfloat16*)Av + (size_t)(bm + srow)*K + scg*8;
    const __hip_bfloat16* a1p = (const __hip_bfloat16*)Av + (size_t)(bm + srow + 32)*K + scg*8;
    const float* a0pf = (const float*)Av + (size_t)(bm + srow)*K + scg*8;
    const float* a1pf = (const float*)Av + (size_t)(bm + srow + 32)*K + scg*8;
    const __hip_bfloat16* w0p = W + (size_t)(bn + srow)*K + scg*8;
    const __hip_bfloat16* w1p = W + (size_t)(bn + srow + 32)*K + scg*8;

    for (int k0 = 0; k0 < K; k0 += 64) {
        int4 va0 = {}, va1 = {};
        if (A32) {
            if (v0) {
                float4 p0 = *(const float4*)(a0pf + k0);
                float4 p1 = *(const float4*)(a0pf + k0 + 4);
                va0.x = f2bf(p0.x) | (f2bf(p0.y) << 16); va0.y = f2bf(p0.z) | (f2bf(p0.w) << 16);
                va0.z = f2bf(p1.x) | (f2bf(p1.y) << 16); va0.w = f2bf(p1.z) | (f2bf(p1.w) << 16);
            }
            if (v1) {
                float4 p0 = *(const float4*)(a1pf + k0);
                float4 p1 = *(const float4*)(a1pf + k0 + 4);
                va1.x = f2bf(p0.x) | (f2bf(p0.y) << 16); va1.y = f2bf(p0.z) | (f2bf(p0.w) << 16);
                va1.z = f2bf(p1.x) | (f2bf(p1.y) << 16); va1.w = f2bf(p1.z) | (f2bf(p1.w) << 16);
            }
        } else {
            if (v0) va0 = *(const int4*)(a0p + k0);
            if (v1) va1 = *(const int4*)(a1p + k0);
        }
        int4 vw0 = *(const int4*)(w0p + k0);
        int4 vw1 = *(const int4*)(w1p + k0);
        __syncthreads();
        *(int4*)(As + wo0) = va0;
        *(int4*)(As + wo1) = va1;
        *(int4*)(Ws + wo0) = vw0;
        *(int4*)(Ws + wo1) = vw1;
        __syncthreads();
        #pragma unroll
        for (int ks = 0; ks < 2; ++ks) {
            int kb = ks*64;
            short8 a0 = *(const short8*)(As + ((baseA0 + kb) ^ swz));
            short8 a1 = *(const short8*)(As + ((baseA1 + kb) ^ swz));
            short8 b0 = *(const short8*)(Ws + ((baseB0 + kb) ^ swz));
            short8 b1 = *(const short8*)(Ws + ((baseB1 + kb) ^ swz));
            acc[0][0] = __builtin_amdgcn_mfma_f32_16x16x32_bf16(a0, b0, acc[0][0], 0, 0, 0);
            acc[0][1] = __builtin_amdgcn_mfma_f32_16x16x32_bf16(a0, b1, acc[0][1], 0, 0, 0);
            acc[1][0] = __builtin_amdgcn_mfma_f32_16x16x32_bf16(a1, b0, acc[1][0], 0, 0, 0);
            acc[1][1] = __builtin_amdgcn_mfma_f32_16x16x32_bf16(a1, b1, acc[1][1], 0, 0, 0);
        }
    }
    float bv0 = bias[bn + wn + lrow];
    float bv1 = bias[bn + wn + 16 + lrow];
    #pragma unroll
    for (int mi = 0; mi < 2; ++mi) {
        #pragma unroll
        for (int r = 0; r < 4; ++r) {
            int row = bm + wm + mi*16 + lq*4 + r;
            if (row >= M) continue;
            #pragma unroll
            for (int ni = 0; ni < 2; ++ni) {
                float v = acc[mi][ni][r] + (ni ? bv1 : bv0);
                if (ACT == 1) v = leaky(v);
                int col = bn + wn + ni*16 + lrow;
                if (RES)       Cres[(size_t)row*N + col] += v;
                else if (OUTF) Cres[(size_t)row*N + col] = v;
                else           Cbf[(size_t)row*N + col] = __float2bfloat16(v);
            }
        }
    }
}

// ---------------- neighborhood attention (bf16 in/out): one thread per (token, head) ----------------
__global__ __launch_bounds__(256) void attn_kernel(const __hip_bfloat16* __restrict__ qkv,
    const float* __restrict__ rpb, __hip_bfloat16* __restrict__ o)
{
    int gid = blockIdx.x*256 + threadIdx.x;
    int tok = gid >> 3;
    if (tok >= TOK) return;
    int head = gid & 7;
    int b = tok / (HF*WF);
    int rem = tok - b*HF*WF;
    int y = rem / WF, x = rem - y*WF;
    const ushort8* qp = (const ushort8*)(qkv + (size_t)tok*384 + head*16);
    float q[16];
    {
        ushort8 u0 = qp[0], u1 = qp[1];
        #pragma unroll
        for (int i = 0; i < 8; ++i) { q[i] = bf2f(u0[i])*0.25f; q[i+8] = bf2f(u1[i])*0.25f; }
    }
    float logits[25];
    float mx = -1e30f;
    #pragma unroll
    for (int di = -2; di <= 2; ++di) {
        int ny = y + di; ny += (ny < 0) ? HF : 0; ny -= (ny >= HF) ? HF : 0;
        #pragma unroll
        for (int dj = -2; dj <= 2; ++dj) {
            int nx = x + dj; nx += (nx < 0) ? WF : 0; nx -= (nx >= WF) ? WF : 0;
            size_t nt = (size_t)((b*HF + ny)*WF + nx);
            const ushort8* kp = (const ushort8*)(qkv + nt*384 + 128 + head*16);
            ushort8 k0 = kp[0], k1 = kp[1];
            float d = 0.f;
            #pragma unroll
            for (int i = 0; i < 8; ++i) d += q[i]*bf2f(k0[i]) + q[i+8]*bf2f(k1[i]);
            d += rpb[head*81 + (di+4)*9 + (dj+4)];
            logits[(di+2)*5 + (dj+2)] = d;
            mx = fmaxf(mx, d);
        }
    }
    float s = 0.f;
    #pragma unroll
    for (int n = 0; n < 25; ++n) { float p = __expf(logits[n]-mx); logits[n] = p; s += p; }
    float invs = 1.f/s;
    float outv[16] = {};
    #pragma unroll
    for (int di = -2; di <= 2; ++di) {
        int ny = y + di; ny += (ny < 0) ? HF : 0; ny -= (ny >= HF) ? HF : 0;
        #pragma unroll
        for (int dj = -2; dj <= 2; ++dj) {
            int nx = x + dj; nx += (nx < 0) ? WF : 0; nx -= (nx >= WF) ? WF : 0;
            size_t nt = (size_t)((b*HF + ny)*WF + nx);
            const ushort8* vp = (const ushort8*)(qkv + nt*384 + 256 + head*16);
            ushort8 v0 = vp[0], v1 = vp[1];
            float p = logits[(di+2)*5 + (dj+2)];
            #pragma unroll
            for (int i = 0; i < 8; ++i) { outv[i] += p*bf2f(v0[i]); outv[i+8] += p*bf2f(v1[i]); }
        }
    }
    __hip_bfloat16* op = o + (size_t)tok*DMOD + head*16;
    #pragma unroll
    for (int i = 0; i < 16; ++i) op[i] = __float2bfloat16(outv[i]*invs);
}

// ---------------- depatch gather ----------------
__global__ __launch_bounds__(256) void degather_kernel(const float* __restrict__ G,
    const float* __restrict__ db, float* __restrict__ yimg)
{
    int idx = blockIdx.x*256 + threadIdx.x;
    int b = idx >> 16;
    int pix = idx & 65535;
    int i = pix >> 8, j = pix & 255;
    int fh0 = i >> 1, fw0 = j >> 1;
    size_t r00 = ((size_t)(b*HF + fh0)*WF + fw0)*64;
    size_t r01 = r00 + 64;
    size_t r10 = r00 + (size_t)WF*64;
    size_t r11 = r10 + 64;
    int wr0 = (2 + (i & 1))*4, wr1 = (i & 1)*4;
    int wc0 = 2 + (j & 1), wc1 = (j & 1);
    #pragma unroll
    for (int c = 0; c < 3; ++c) {
        int e = c*16;
        float v = db[c]
                + G[r00 + e + wr0 + wc0] + G[r01 + e + wr0 + wc1]
                + G[r10 + e + wr1 + wc0] + G[r11 + e + wr1 + wc1];
        yimg[((size_t)(b*3 + c) << 16) + pix] = v;
    }
}

// ---------------- residual conv tail ----------------
__global__ __launch_bounds__(256) void res_kernel(const float* __restrict__ y,
    const float* __restrict__ w1, const float* __restrict__ b1,
    const float* __restrict__ w2, const float* __restrict__ b2, float* __restrict__ out)
{
    int idx = blockIdx.x*256 + threadIdx.x;
    int b = idx >> 16;
    int pix = idx & 65535;
    int i = pix >> 8, j = pix & 255;
    float yv[3][5][5];
    #pragma unroll
    for (int c = 0; c < 3; ++c) {
        #pragma unroll
        for (int u = 0; u < 5; ++u) {
            int ii = (i + u - 2 + 256) & 255;
            #pragma unroll
            for (int v = 0; v < 5; ++v) {
                int jj = (j + v - 2 + 256) & 255;
                yv[c][u][v] = y[((size_t)(b*3 + c)*256 + ii)*256 + jj];
            }
        }
    }
    float r1[12];
    #pragma unroll
    for (int rc = 0; rc < 12; ++rc) {
        float a = b1[rc];
        #pragma unroll
        for (int c = 0; c < 3; ++c)
            #pragma unroll
            for (int u = 0; u < 5; ++u)
                #pragma unroll
                for (int v = 0; v < 5; ++v)
                    a += yv[c][u][v] * w1[rc*75 + c*25 + u*5 + v];
        r1[rc] = leaky(a);
    }
    #pragma unroll
    for (int c = 0; c < 3; ++c) {
        float a = b2[c];
        #pragma unroll
        for (int rc = 0; rc < 12; ++rc) a += r1[rc]*w2[c*12 + rc];
        out[((size_t)(b*3 + c)*256 + i)*256 + j] = yv[c][2][2] + a;
    }
}

extern "C" void kernel_launch(void* const* d_in, const int* in_sizes, int n_in,
                              void* d_out, int out_size, void* d_ws, size_t ws_size,
                              hipStream_t stream)
{
    const float* x      = (const float*)d_in[0];
    const float* pos_w  = (const float*)d_in[1];
    const float* pos_b  = (const float*)d_in[2];
    const float* patch_w= (const float*)d_in[3];
    const float* patch_b= (const float*)d_in[4];
    const float* ln1_g  = (const float*)d_in[5];
    const float* ln1_b  = (const float*)d_in[6];
    const float* qkv_w  = (const float*)d_in[7];
    const float* qkv_b  = (const float*)d_in[8];
    const float* rpb    = (const float*)d_in[9];
    const float* proj_w = (const float*)d_in[10];
    const float* proj_b = (const float*)d_in[11];
    const float* ln2_g  = (const float*)d_in[12];
    const float* ln2_b  = (const float*)d_in[13];
    const float* fc1_w  = (const float*)d_in[14];
    const float* fc1_b  = (const float*)d_in[15];
    const float* fc2_w  = (const float*)d_in[16];
    const float* fc2_b  = (const float*)d_in[17];
    const float* dep_w  = (const float*)d_in[18];
    const float* dep_b  = (const float*)d_in[19];
    const float* rc1_w  = (const float*)d_in[20];
    const float* rc1_b  = (const float*)d_in[21];
    const float* rc2_w  = (const float*)d_in[22];
    const float* rc2_b  = (const float*)d_in[23];

    const size_t SZ = (size_t)TOK * 128;
    char* w = (char*)d_ws;
    float* f            = (float*)w;            w += SZ*4;
    __hip_bfloat16* yln = (__hip_bfloat16*)w;   w += SZ*2;          // LN output
    __hip_bfloat16* ao  = (__hip_bfloat16*)w;   w += SZ*2;          // attn output
    __hip_bfloat16* qkvb= (__hip_bfloat16*)w;   w += (size_t)TOK*384*2;
    __hip_bfloat16* hb  = (__hip_bfloat16*)w;   w += (size_t)TOK*512*2;
    float* yimg         = (float*)w;            w += (size_t)BDIM*3*65536*4;
    __hip_bfloat16* wq  = (__hip_bfloat16*)w;   w += (size_t)NQ*2;
    __hip_bfloat16* wp  = (__hip_bfloat16*)w;   w += (size_t)NPJ*2;
    __hip_bfloat16* w1  = (__hip_bfloat16*)w;   w += (size_t)N1*2;
    __hip_bfloat16* w2  = (__hip_bfloat16*)w;   w += (size_t)N2*2;
    __hip_bfloat16* wpat= (__hip_bfloat16*)w;   w += (size_t)NPAT*2;
    __hip_bfloat16* wdep= (__hip_bfloat16*)w;   w += (size_t)NDEP*2;
    float* zero64       = (float*)w;            w += 64*4;

    // disjoint lifetimes: im2col output aliases qkvb, depatch G aliases hb
    __hip_bfloat16* icol = qkvb;    // TOK*64 bf16
    float* G             = (float*)hb;  // TOK*64 f32

    const int PREP_TOT = NQ + NPJ + N1 + N2 + NPAT + NDEP + 64;
    prep_weights<<<(PREP_TOT + 255)/256, 256, 0, stream>>>(
        qkv_w, proj_w, fc1_w, fc2_w, patch_w, dep_w, wq, wp, w1, w2, wpat, wdep, zero64);

    im2col_kernel<<<BDIM*HF, 256, 0, stream>>>(x, pos_w, pos_b, icol);

    const int GM = (TOK + 63)/64;     // 521

    // patchify: f = icol @ wpat^T + b, fused LN1(l=0) -> yln
    gemmF_kernel<0,0,1,1><<<dim3(GM,1), 256, 0, stream>>>(icol, wpat, patch_b,
        ln1_g, ln1_b, nullptr, f, yln, TOK, 128, 64);

    for (int l = 0; l < 3; ++l) {
        // qkv = yln @ Wq^T + b
        gemmF_kernel<0,0,0,0><<<dim3(GM,3), 256, 0, stream>>>(yln, wq + (size_t)l*384*128,
            qkv_b + l*384, nullptr, nullptr, qkvb, nullptr, nullptr, TOK, 384, 128);
        attn_kernel<<<(TOK*8 + 255)/256, 256, 0, stream>>>(qkvb, rpb + l*8*81, ao);
        // f += ao @ Wp^T + b, fused LN2 -> yln
        gemmF_kernel<0,1,0,1><<<dim3(GM,1), 256, 0, stream>>>(ao, wp + (size_t)l*128*128,
            proj_b + l*128, ln2_g + l*128, ln2_b + l*128, nullptr, f, yln, TOK, 128, 128);
        // hb = leaky(yln @ W1^T + b)
        gemmF_kernel<1,0,0,0><<<dim3(GM,4), 256, 0, stream>>>(yln, w1 + (size_t)l*512*128,
            fc1_b + l*512, nullptr, nullptr, hb, nullptr, nullptr, TOK, 512, 128);
        // f += hb @ W2^T + b, fused LN1(l+1) -> yln (skip LN on last layer)
        if (l < 2)
            gemmF_kernel<0,1,0,1><<<dim3(GM,1), 256, 0, stream>>>(hb, w2 + (size_t)l*128*512,
                fc2_b + l*128, ln1_g + (l+1)*128, ln1_b + (l+1)*128, nullptr, f, yln, TOK, 128, 512);
        else
            gemmF_kernel<0,1,0,0><<<dim3(GM,1), 256, 0, stream>>>(hb, w2 + (size_t)l*128*512,
                fc2_b + l*128, nullptr, nullptr, nullptr, f, nullptr, TOK, 128, 512);
    }

    // depatchify: G[T,64] = f[T,128] @ wdep[64,128]^T
    mgemm_kernel<0,0,1,1><<<dim3(GM,1), 256, 0, stream>>>(f, wdep, zero64,
        nullptr, G, TOK, 64, 128);
    degather_kernel<<<512, 256, 0, stream>>>(G, dep_b, yimg);

    res_kernel<<<512, 256, 0, stream>>>(yimg, rc1_w, rc1_b, rc2_w, rc2_b, (float*)d_out);
}